// Round 4
// baseline (192.542 us; speedup 1.0000x reference)
//
#include <hip/hip_runtime.h>
#include <stdint.h>

#define GM 4096
#define GN 4096
#define GK 4096
#define QW (GN/8)   /* 512 packed words per k-row */

typedef __attribute__((ext_vector_type(4))) int   i32x4;
typedef __attribute__((ext_vector_type(8))) short bf16x8;
typedef __attribute__((ext_vector_type(4))) float f32x4;

#define AS1 __attribute__((address_space(1)))
#define AS3 __attribute__((address_space(3)))

static __device__ __forceinline__ void glds16(const void* g, void* l) {
  __builtin_amdgcn_global_load_lds((const AS1 uint32_t*)g, (AS3 uint32_t*)l, 16, 0, 0);
}

static __device__ __forceinline__ uint32_t bf16pack_rn(float hi, float lo) {
  uint32_t h = __float_as_uint(hi) + 0x8000u;
  uint32_t l = __float_as_uint(lo) + 0x8000u;
  return __builtin_amdgcn_perm(h, l, 0x07060302u);
}

static __device__ __forceinline__ uint32_t pack4i8(int b0, int b1, int b2, int b3) {
  return ((uint32_t)b0 & 255u) | (((uint32_t)b1 & 255u) << 8) |
         (((uint32_t)b2 & 255u) << 16) | (((uint32_t)b3 & 255u) << 24);
}

// ---------- Fused prep kernel: a_quant ∥ w_quant(local winv) ∥ w_scale -------
__global__ void __launch_bounds__(256) prep(const float* __restrict__ A,
                                            const float* __restrict__ S,
                                            const uint32_t* __restrict__ Q,
                                            int8_t* __restrict__ Ai,
                                            float* __restrict__ ascale,
                                            int8_t* __restrict__ Wt,
                                            float* __restrict__ wscale) {
  __shared__ uint32_t T32[128 * 32];             // 16 KB (w_quant role)
  __shared__ float4   red[8][32];                // 4 KB  (winv reduce)
  __shared__ float    winv_l[128];

  const int b   = blockIdx.x;
  const int tid = threadIdx.x;

  if (b < 1024) {
    // ---- a_quant role: A fp32 -> i8 per-row quant, one wave per row ----
    const int lane = tid & 63;
    const int row  = b * 4 + (tid >> 6);
    const float* src = A + (size_t)row * GK;
    float4 v[16];
    float m = 0.f;
    #pragma unroll
    for (int i = 0; i < 16; ++i) {
      v[i] = *(const float4*)(src + i * 256 + lane * 4);
      m = fmaxf(m, fmaxf(fmaxf(fabsf(v[i].x), fabsf(v[i].y)),
                         fmaxf(fabsf(v[i].z), fabsf(v[i].w))));
    }
    #pragma unroll
    for (int off = 32; off >= 1; off >>= 1)
      m = fmaxf(m, __shfl_xor(m, off, 64));
    const float rmax = fmaxf(m, 1e-20f);
    const float inv  = 127.0f / rmax;
    #pragma unroll
    for (int i = 0; i < 16; ++i) {
      uint32_t bb = pack4i8((int)__builtin_rintf(v[i].x * inv),
                            (int)__builtin_rintf(v[i].y * inv),
                            (int)__builtin_rintf(v[i].z * inv),
                            (int)__builtin_rintf(v[i].w * inv));
      *(uint32_t*)(Ai + (size_t)row * GK + i * 256 + lane * 4) = bb;
    }
    if (lane == 0) ascale[row] = rmax * (1.0f / 127.0f);
  } else if (b < 2048) {
    // ---- w_quant role: int4 -> i8 W^T [N][K], coalesced + LDS transpose ----
    const int wb = b - 1024;
    const int n0 = (wb & 31) * 128;
    const int k0 = (wb >> 5) * 128;
    const int g  = wb >> 5;
    const int w  = tid & 15;
    const int kb = tid >> 4;

    // local winv: max over 32 groups for this block's 128 columns
    {
      const int c4 = tid & 31;          // col quad (4 cols)
      const int g8 = tid >> 5;          // 0..7, each covers 4 groups
      float4 m4 = make_float4(0.f, 0.f, 0.f, 0.f);
      #pragma unroll
      for (int gg = 0; gg < 4; ++gg) {
        float4 sv = *(const float4*)(S + (size_t)(g8 * 4 + gg) * GN + n0 + c4 * 4);
        m4.x = fmaxf(m4.x, sv.x); m4.y = fmaxf(m4.y, sv.y);
        m4.z = fmaxf(m4.z, sv.z); m4.w = fmaxf(m4.w, sv.w);
      }
      red[g8][c4] = m4;
      __syncthreads();
      if (g8 == 0) {
        float4 m = red[0][c4];
        #pragma unroll
        for (int rr = 1; rr < 8; ++rr) {
          float4 o = red[rr][c4];
          m.x = fmaxf(m.x, o.x); m.y = fmaxf(m.y, o.y);
          m.z = fmaxf(m.z, o.z); m.w = fmaxf(m.w, o.w);
        }
        winv_l[c4 * 4 + 0] = 127.0f / (8.0f * m.x);
        winv_l[c4 * 4 + 1] = 127.0f / (8.0f * m.y);
        winv_l[c4 * 4 + 2] = 127.0f / (8.0f * m.z);
        winv_l[c4 * 4 + 3] = 127.0f / (8.0f * m.w);
      }
      __syncthreads();
    }

    float r[8], c[8];
    {
      const float* sp = S + (size_t)g * GN + n0 + w * 8;
      float4 sa = *(const float4*)sp, sb = *(const float4*)(sp + 4);
      float4 ia = *(const float4*)&winv_l[w * 8];
      float4 ib = *(const float4*)&winv_l[w * 8 + 4];
      const float sv[8] = {sa.x, sa.y, sa.z, sa.w, sb.x, sb.y, sb.z, sb.w};
      const float iv[8] = {ia.x, ia.y, ia.z, ia.w, ib.x, ib.y, ib.z, ib.w};
      #pragma unroll
      for (int j = 0; j < 8; ++j) { r[j] = sv[j] * iv[j]; c[j] = -8.0f * r[j]; }
    }

    const int swz = 4 * (w & 7);
    #pragma unroll
    for (int c2 = 0; c2 < 2; ++c2) {
      uint32_t q[4];
      #pragma unroll
      for (int i = 0; i < 4; ++i)
        q[i] = Q[(size_t)(k0 + c2 * 64 + kb * 4 + i) * QW + (n0 >> 3) + w];
      const int kword = c2 * 16 + kb;
      #pragma unroll
      for (int j = 0; j < 8; ++j) {
        int bb[4];
        #pragma unroll
        for (int i = 0; i < 4; ++i) {
          float nib = (float)((q[i] >> (4 * j)) & 0xFu);
          bb[i] = (int)__builtin_rintf(fmaf(nib, r[j], c[j]));
        }
        T32[(w * 8 + j) * 32 + (kword ^ swz)] = pack4i8(bb[0], bb[1], bb[2], bb[3]);
      }
    }
    __syncthreads();
    #pragma unroll
    for (int p = 0; p < 4; ++p) {
      int idx = p * 256 + tid;
      int n = idx >> 3, gr = idx & 7;
      uint4 v = *(const uint4*)(&T32[n * 32 + (gr ^ ((n >> 3) & 7)) * 4]);
      *(uint4*)(Wt + (size_t)(n0 + n) * GK + k0 + gr * 16) = v;
    }
  } else {
    // ---- w_scale role: per-column wscale = 8*max_g s / 127 (gemm epilogue) --
    const int n = (b - 2048) * 256 + tid;
    float m = 0.f;
    #pragma unroll 8
    for (int gg = 0; gg < 32; ++gg) m = fmaxf(m, S[(size_t)gg * GN + n]);
    wscale[n] = m * (8.0f / 127.0f);
  }
}

// ---------- Kernel 3: i8 GEMM, 128x256 tile, BK=64, 3-buffer, 2 blocks/CU ----
// Round-4: fixes round-3's RACE (reads were issued before the barrier, so a
// wave could read LDS chunks other waves' glds hadn't landed). Schedule per
// 64-K step t (buffer = t%3, static via x3 unroll):
//   VM3: own tile-t glds landed (depth 2; never 0)
//   BARRIER: ALL waves' tile-t glds landed; also happens-after all waves'
//            step t-1 ds_reads retired (consumed by step t-1 MFMAs via
//            compiler lgkm waits) -> safe to overwrite buf[(t+2)%3]
//   STAGE tile t+2 -> buf[(t+2)%3]   (3 glds16)
//   ds_read buf[t%3] (8x b128) ; 16 MFMA
// One barrier per K-step. LDS 3 x 24 KB = 72 KB; VGPR <=128 via
// __launch_bounds__(512,4) -> 2 blocks/CU: one block's LDS window overlaps
// the other's MFMA window (m114 cross-wave pipe overlap).
// Swizzle (64-B rows): phys chunk = logical ^ (row&3), pre-swizzled glds
// SOURCE + same XOR on read. i8 accumulation exact -> bitwise-identical C.
__global__ void __launch_bounds__(512, 4) gemm_i8(const int8_t* __restrict__ Ai,
                                                  const int8_t* __restrict__ Wi,
                                                  const float* __restrict__ ascale,
                                                  const float* __restrict__ wscale,
                                                  float* __restrict__ C) {
  __shared__ __align__(16) int8_t As[3][128 * 64];   // 3 x 8 KB
  __shared__ __align__(16) int8_t Bs[3][256 * 64];   // 3 x 16 KB

  const int tid = threadIdx.x;
  // bijective XCD swizzle (512 blocks, 512 % 8 == 0)
  const int bid = blockIdx.y * gridDim.x + blockIdx.x;
  const int swb = ((bid & 7) << 6) | (bid >> 3);
  const int m0  = (swb >> 4) * 128;     // 32 m-tiles
  const int n0  = (swb & 15) * 256;     // 16 n-tiles

  const int lane = tid & 63;
  const int wid  = tid >> 6;
  const int wm   = wid >> 2;        // 0..1  -> m-offset wm*64
  const int wn   = wid & 3;         // 0..3  -> n-offset wn*64
  const int col  = lane & 15;
  const int quad = lane >> 4;

  // ---- staging: thread t -> row t>>2 (0..127), phys chunk t&3 ----
  const int srow = tid >> 2;
  const int qo   = ((tid & 3) ^ (srow & 3)) << 4;    // pre-swizzled source chunk
  const int8_t* Asrc  = Ai + (size_t)(m0 + srow) * GK + qo;
  const int8_t* Bsrc  = Wi + (size_t)(n0 + srow) * GK + qo;
  const int8_t* Bsrc2 = Bsrc + (size_t)128 * GK;

#define STAGE(b, ko) do {                                    \
    glds16(Asrc  + (ko), &As[b][tid * 16]);                  \
    glds16(Bsrc  + (ko), &Bs[b][tid * 16]);                  \
    glds16(Bsrc2 + (ko), &Bs[b][8192 + tid * 16]);           \
  } while (0)

  // ---- fragment reads: row = base + col, phys chunk = quad ^ (col&3) ----
  const int cq  = ((quad ^ (col & 3)) << 4);
  const int aRd = (wm * 64 + col) * 64 + cq;
  const int bRd = (wn * 64 + col) * 64 + cq;

  i32x4 af[4], bf[4];
  i32x4 acc[4][4];
  #pragma unroll
  for (int i = 0; i < 4; ++i)
    #pragma unroll
    for (int j = 0; j < 4; ++j)
      acc[i][j] = (i32x4){0, 0, 0, 0};

#define LD_(b) do {                                                   \
    _Pragma("unroll")                                                 \
    for (int x_ = 0; x_ < 4; ++x_) {                                  \
      af[x_] = *(const i32x4*)(&As[b][aRd + x_ * 1024]);              \
      bf[x_] = *(const i32x4*)(&Bs[b][bRd + x_ * 1024]);              \
    }                                                                 \
  } while (0)
#define MFMA16_() do {                                                \
    _Pragma("unroll")                                                 \
    for (int m_ = 0; m_ < 4; ++m_)                                    \
      _Pragma("unroll")                                               \
      for (int n_ = 0; n_ < 4; ++n_)                                  \
        acc[m_][n_] = __builtin_amdgcn_mfma_i32_16x16x64_i8(          \
            af[m_], bf[n_], acc[m_][n_], 0, 0, 0);                    \
  } while (0)
#define VM3()   asm volatile("s_waitcnt vmcnt(3)" ::: "memory")
#define BARM()  asm volatile("s_barrier" ::: "memory")
#define PRIO1() __builtin_amdgcn_s_setprio(1)
#define PRIO0() __builtin_amdgcn_s_setprio(0)

// one 64-K step: tile t from buf B_CUR, stage tile t+2 into buf B_NXT
#define STEP(B_CUR, B_NXT, KO_NXT) do {                               \
    VM3();                        /* own tile-t loads landed */       \
    BARM();                       /* all waves' -> reads safe  */     \
    STAGE(B_NXT, (KO_NXT));       /* overwrite: readers >=1 bar old */\
    LD_(B_CUR);                                                       \
    PRIO1(); MFMA16_(); PRIO0();                                      \
  } while (0)

  // ---- prologue: tile0 -> buf0, tile1 -> buf1 (6 glds outstanding) ----
  STAGE(0, 0);
  STAGE(1, 64);

  // ---- main loop: 64 K-steps = 21 x3-unrolled + 1 tail ----
  for (int it = 0; it < 21; ++it) {
    const int t = 3 * it;
    STEP(0, 2, ((t + 2) & 63) << 6);   // step t
    STEP(1, 0, ((t + 3) & 63) << 6);   // step t+1
    STEP(2, 1, ((t + 4) & 63) << 6);   // step t+2
  }
  // tail: step 63 (buf0 holds tile 63, staged at step 61)
  VM3();
  BARM();
  LD_(0);
  PRIO1(); MFMA16_(); PRIO0();

  // ---- epilogue: C/D col=lane&15, row=quad*4+reg (verified layout) ----
  #pragma unroll
  for (int mt = 0; mt < 4; ++mt) {
    const int rbase = m0 + wm * 64 + mt * 16 + quad * 4;
    float4 a4 = *(const float4*)(ascale + rbase);
    const float ar[4] = {a4.x, a4.y, a4.z, a4.w};
    #pragma unroll
    for (int nt = 0; nt < 4; ++nt) {
      const int cbase = n0 + wn * 64 + nt * 16 + col;
      const float ws = wscale[cbase];
      #pragma unroll
      for (int r = 0; r < 4; ++r)
        C[(size_t)(rbase + r) * GN + cbase]
          = (float)acc[mt][nt][r] * (ar[r] * ws);
    }
  }
#undef STAGE
#undef LD_
#undef MFMA16_
#undef VM3
#undef BARM
#undef PRIO1
#undef PRIO0
#undef STEP
}

// ---------------- Fallback: fused dequant GEMM (round-2 kernel) ----------------
#define BM 128
#define BN 128
#define BK 32

__global__ void __launch_bounds__(256) w4a32_gemm(
    const float* __restrict__ A,
    const float* __restrict__ S,
    const uint32_t* __restrict__ Q,
    float* __restrict__ C)
{
  __shared__ __align__(16) ushort As[BM*BK];
  __shared__ __align__(16) ushort Bs[BN*BK];

  const int tid  = threadIdx.x;
  const int m0   = blockIdx.y*BM;
  const int n0   = blockIdx.x*BN;
  const int wcol  = tid & 15;
  const int kpair = tid >> 4;
  const int ln   = tid & 63;
  const int wid  = tid >> 6;
  const int wm   = (wid >> 1) * 64;
  const int wn   = (wid & 1) * 64;
  const int col  = ln & 15;
  const int quad = ln >> 4;

  f32x4 acc[4][4];
  #pragma unroll
  for (int i=0;i<4;++i)
    #pragma unroll
    for (int j=0;j<4;++j)
      acc[i][j] = (f32x4){0.f,0.f,0.f,0.f};

  float sv[8], cv[8];
  float4 spf0, spf1;

  const float*    Abase = A + (size_t)m0 * GK;
  const uint32_t* Qbase = Q + (size_t)(n0>>3) + wcol;

  {
    const float* sp = S + n0 + wcol*8;
    spf0 = *(const float4*)sp;
    spf1 = *(const float4*)(sp + 4);
  }

  float4 a4[4];
  uint32_t wqa, wqb;
  #pragma unroll
  for (int i=0;i<4;++i) {
    int f = tid + i*256;
    a4[i] = *(const float4*)(Abase + (size_t)(f>>3)*GK + ((f&7)*4));
  }
  wqa = Qbase[(size_t)(2*kpair)   * QW];
  wqb = Qbase[(size_t)(2*kpair+1) * QW];

  for (int k0 = 0; k0 < GK; k0 += BK) {
    if ((k0 & 127) == 0) {
      sv[0]=spf0.x; sv[1]=spf0.y; sv[2]=spf0.z; sv[3]=spf0.w;
      sv[4]=spf1.x; sv[5]=spf1.y; sv[6]=spf1.z; sv[7]=spf1.w;
      #pragma unroll
      for (int j=0;j<8;++j) cv[j] = -8.0f * sv[j];
    }

    #pragma unroll
    for (int i=0;i<4;++i) {
      int f = tid + i*256;
      int row = f>>3, c4 = f&7;
      *(uint2*)(&As[row*BK + c4*4]) =
        make_uint2(bf16pack_rn(a4[i].y, a4[i].x), bf16pack_rn(a4[i].w, a4[i].z));
    }

    {
      const int kk = (2*kpair) ^ (8*(wcol&3));
      #pragma unroll
      for (int j=0;j<8;++j) {
        float fa = (float)((wqa >> (4*j)) & 0xFu);
        float fb = (float)((wqb >> (4*j)) & 0xFu);
        float wa = fmaf(fa, sv[j], cv[j]);
        float wb = fmaf(fb, sv[j], cv[j]);
        int n = wcol*8 + j;
        *(uint32_t*)(&Bs[n*BK + kk]) = bf16pack_rn(wb, wa);
      }
    }

    int kn = k0 + BK; if (kn >= GK) kn = 0;
    if ((kn & 127) == 0) {
      const float* sp = S + (size_t)(kn>>7)*GN + n0 + wcol*8;
      spf0 = *(const float4*)sp;
      spf1 = *(const float4*)(sp + 4);
    }
    #pragma unroll
    for (int i=0;i<4;++i) {
      int f = tid + i*256;
      a4[i] = *(const float4*)(Abase + (size_t)(f>>3)*GK + kn + ((f&7)*4));
    }
    wqa = Qbase[(size_t)(kn + 2*kpair)   * QW];
    wqb = Qbase[(size_t)(kn + 2*kpair+1) * QW];

    __syncthreads();

    bf16x8 af[4], bfr[4];
    #pragma unroll
    for (int t=0;t<4;++t) {
      af[t] = *(const bf16x8*)(&As[(wm + t*16 + col)*BK + quad*8]);
      int n = wn + t*16 + col;
      int kk = (quad*8) ^ (8*((n>>3)&3));
      bfr[t] = *(const bf16x8*)(&Bs[n*BK + kk]);
    }
    #pragma unroll
    for (int mt=0;mt<4;++mt)
      #pragma unroll
      for (int nt=0;nt<4;++nt)
        acc[mt][nt] = __builtin_amdgcn_mfma_f32_16x16x32_bf16(
                          af[mt], bfr[nt], acc[mt][nt], 0, 0, 0);

    __syncthreads();
  }

  #pragma unroll
  for (int mt=0;mt<4;++mt)
    #pragma unroll
    for (int nt=0;nt<4;++nt)
      #pragma unroll
      for (int r=0;r<4;++r)
        C[(size_t)(m0 + wm + mt*16 + quad*4 + r)*GN + n0 + wn + nt*16 + col]
          = acc[mt][nt][r];
}

extern "C" void kernel_launch(void* const* d_in, const int* in_sizes, int n_in,
                              void* d_out, int out_size, void* d_ws, size_t ws_size,
                              hipStream_t stream) {
  const float*    A = (const float*)d_in[0];
  const float*    S = (const float*)d_in[1];
  const uint32_t* Q = (const uint32_t*)d_in[2];
  float*          C = (float*)d_out;

  const size_t need = (size_t)GM * GK + (size_t)GN * GK + 3 * 4096 * 4 + 4096;
  if (ws_size >= need) {
    int8_t* Ai  = (int8_t*)d_ws;                          // [M][K] i8, 16 MB
    int8_t* Wt  = Ai + (size_t)GM * GK;                   // [N][K] i8, 16 MB
    float* ascale = (float*)(Wt + (size_t)GN * GK);       // 4096 f32
    float* wscale = ascale + 4096;
    prep<<<dim3(1024 + 1024 + 16), dim3(256), 0, stream>>>(A, S, Q, Ai, ascale, Wt, wscale);
    gemm_i8<<<dim3(16, 32), dim3(512), 0, stream>>>(Ai, Wt, ascale, wscale, C);
  } else {
    w4a32_gemm<<<dim3(GN / BN, GM / BM), dim3(256), 0, stream>>>(A, S, Q, C);
  }
}